// Round 2
// baseline (269.196 us; speedup 1.0000x reference)
//
#include <hip/hip_runtime.h>
#include <hip/hip_bf16.h>

// ConvCaps spectral routing.
//   activations[b,o] = sigmoid(lambda_max(G)/tr(G) - bias[o])
//   poses[b,o,:]     = top eigenvector of G, matching LAPACK ssyevd sign conventions.
// G[b,o] built from per-(b,l) second-moment matrices M (spatial weight sharing).
// Output dtype: fp32 (harness reads 4-byte floats; bf16 writes fail with the
// observed 1.14 "pose-in-high-bytes" error signature).

#define NSPAT 196

__device__ __forceinline__ float wsum64(float x) {
  x += __shfl_xor(x, 32);
  x += __shfl_xor(x, 16);
  x += __shfl_xor(x, 8);
  x += __shfl_xor(x, 4);
  x += __shfl_xor(x, 2);
  x += __shfl_xor(x, 1);
  return x;
}

// ---------------- kernel A: per-(b,l) moment matrices -----------------------
// M[b*32+l][p][q] = sum_s a(b,s,l)^2 * pose(b,s,l,p) * pose(b,s,l,q)
__global__ __launch_bounds__(256) void moments_kernel(const float* __restrict__ in,
                                                      float* __restrict__ Mout) {
  int b = blockIdx.x >> 5;
  int l = blockIdx.x & 31;
  __shared__ float ps[NSPAT][16];
  __shared__ float as2[NSPAT];
  int t = threadIdx.x;
  for (int j = t; j < NSPAT * 16; j += 256) {
    int s = j >> 4, p = j & 15;
    ps[s][p] = in[((size_t)(b * NSPAT + s)) * 544 + l * 16 + p];
  }
  for (int s = t; s < NSPAT; s += 256) {
    float a = in[((size_t)(b * NSPAT + s)) * 544 + 512 + l];
    as2[s] = a * a;
  }
  __syncthreads();
  int p = t >> 4, q = t & 15;
  float acc = 0.f;
  for (int s = 0; s < NSPAT; ++s) {
    // symmetric-exact: product commutative, same fma order for (p,q) and (q,p)
    acc += as2[s] * (ps[s][p] * ps[s][q]);
  }
  Mout[(size_t)blockIdx.x * 256 + t] = acc;
}

// ---------------- kernel B: contract moments with weights -> gram ----------
// G[b*32+o][(i1,k1)][(i2,k2)] = sum_l sum_j sum_j2 W_l[j,k1] W_l[j2,k2] M[b,l][(i1,j)][(i2,j2)]
__global__ __launch_bounds__(256) void gram_kernel(const float* __restrict__ Min,
                                                   const float* __restrict__ W,
                                                   float* __restrict__ Gout) {
  int b = blockIdx.x >> 5;
  int o = blockIdx.x & 31;
  int t = threadIdx.x;
  __shared__ float Ms[256];
  __shared__ float Ws[16];
  int p = t >> 4, q = t & 15;
  int i1 = p >> 2, k1 = p & 3, i2 = q >> 2, k2 = q & 3;
  float acc = 0.f;
  for (int l = 0; l < 32; ++l) {
    Ms[t] = Min[((size_t)(b * 32 + l)) * 256 + t];
    if (t < 16) Ws[t] = W[((size_t)(l * 32 + o)) * 16 + t];
    __syncthreads();
    float sub = 0.f;
    for (int j2 = 0; j2 < 4; ++j2) {
      float inner = 0.f;
      for (int j = 0; j < 4; ++j)
        inner += Ws[j * 4 + k1] * Ms[(i1 * 4 + j) * 16 + (i2 * 4 + j2)];
      sub += Ws[j2 * 4 + k2] * inner;
    }
    acc += sub;
    __syncthreads();
  }
  Gout[(size_t)blockIdx.x * 256 + t] = acc;
}

// ---------------- LAPACK fp32 helpers (sign-faithful) ----------------------
#define EPSF    5.9604645e-08f   /* slamch('E') = 2^-24 */
#define EPS2F   (EPSF * EPSF)
#define SAFMINF 1.1754944e-38f   /* slamch('S') */

__device__ __forceinline__ float ssign(float a, float b) {
  return (b >= 0.f) ? fabsf(a) : -fabsf(a);
}

__device__ __forceinline__ float slapy2(float x, float y) {
  float xa = fabsf(x), ya = fabsf(y);
  float w = fmaxf(xa, ya), z = fminf(xa, ya);
  if (z == 0.f) return w;
  float t = z / w;
  return w * sqrtf(1.f + t * t);
}

// LAPACK >= 3.10 slartg convention (c >= 0, r carries sign of f)
__device__ __forceinline__ void slartg(float f, float g, float* c, float* s, float* r) {
  if (g == 0.f) {
    *c = 1.f; *s = 0.f; *r = f;
  } else if (f == 0.f) {
    *c = 0.f; *s = (g >= 0.f) ? 1.f : -1.f; *r = fabsf(g);
  } else {
    float d = sqrtf(f * f + g * g);
    *c = fabsf(f) / d;
    float rr = (f >= 0.f) ? d : -d;
    *s = g / rr;
    *r = rr;
  }
}

__device__ __forceinline__ void slaev2(float a, float b, float c,
                                       float* rt1, float* rt2, float* cs1, float* sn1) {
  float sm = a + c;
  float df = a - c;
  float adf = fabsf(df);
  float tb = b + b;
  float ab = fabsf(tb);
  float acmx, acmn;
  if (fabsf(a) > fabsf(c)) { acmx = a; acmn = c; } else { acmx = c; acmn = a; }
  float rt;
  if (adf > ab)      { float t = ab / adf; rt = adf * sqrtf(1.f + t * t); }
  else if (adf < ab) { float t = adf / ab; rt = ab * sqrtf(1.f + t * t); }
  else               { rt = ab * sqrtf(2.f); }
  int sgn1;
  if (sm < 0.f) {
    *rt1 = 0.5f * (sm - rt); sgn1 = -1;
    *rt2 = (acmx / *rt1) * acmn - (b / *rt1) * b;
  } else if (sm > 0.f) {
    *rt1 = 0.5f * (sm + rt); sgn1 = 1;
    *rt2 = (acmx / *rt1) * acmn - (b / *rt1) * b;
  } else {
    *rt1 = 0.5f * rt; *rt2 = -0.5f * rt; sgn1 = 1;
  }
  float cs; int sgn2;
  if (df >= 0.f) { cs = df + rt; sgn2 = 1; }
  else           { cs = df - rt; sgn2 = -1; }
  float acs = fabsf(cs);
  float c1, s1;
  if (acs > ab) {
    float ct = -tb / cs;
    s1 = 1.f / sqrtf(1.f + ct * ct);
    c1 = ct * s1;
  } else {
    if (ab == 0.f) { c1 = 1.f; s1 = 0.f; }
    else {
      float tn = -cs / tb;
      c1 = 1.f / sqrtf(1.f + tn * tn);
      s1 = tn * c1;
    }
  }
  if (sgn1 == sgn2) { float tn = c1; c1 = -s1; s1 = tn; }
  *cs1 = c1; *sn1 = s1;
}

// ---------------- kernel C: one wave per 16x16 eig problem -----------------
// Replicates ssyevd fp32: ssytd2(lower) + ssteqr('I') + sormtr on winning column.
// All 64 lanes run scalar recurrences redundantly (d/e/tau private per lane);
// lanes 0..15 own matrix rows -> every LDS access after the load barrier is
// lane-local, so no further barriers are needed.
__global__ __launch_bounds__(64) void eig_kernel(const float* __restrict__ G,
                                                 const float* __restrict__ bias,
                                                 float* __restrict__ out) {
  const int pid = blockIdx.x;   // b*32 + o
  const int lane = threadIdx.x;
  __shared__ float A[16][17];      // symmetric working matrix / householder vectors
  __shared__ float Zr[16][17];     // Z row-major: Zr[row][col]
  __shared__ float ddl[64][17];    // per-lane replicated d
  __shared__ float eel[64][17];    // per-lane replicated e
  __shared__ float ttl[64][17];    // per-lane replicated tau

  // load + symmetrize (use lower triangle), init Z = I
  for (int k = 0; k < 4; ++k) {
    int t = lane + 64 * k;
    int r = t >> 4, c = t & 15;
    int rr = r >= c ? r : c;
    int cc = r >= c ? c : r;
    A[r][c] = G[(size_t)pid * 256 + rr * 16 + cc];
    Zr[r][c] = (r == c) ? 1.f : 0.f;
  }
  float trc = (lane < 16) ? G[(size_t)pid * 256 + lane * 17] : 0.f;
  float trace = wsum64(trc);
  __syncthreads();

  // ---- ssytd2 (lower) ----
  for (int i = 0; i < 15; ++i) {
    float acol = (lane < 16) ? A[lane][i] : 0.f;
    float alpha = __shfl(acol, i + 1);
    float x = (lane >= i + 2 && lane < 16) ? acol : 0.f;
    float xns = wsum64(x * x);
    if (xns == 0.f) {
      eel[lane][i] = alpha;
      ttl[lane][i] = 0.f;
      continue;
    }
    float beta = (alpha >= 0.f ? -1.f : 1.f) * sqrtf(alpha * alpha + xns);
    float taui = (beta - alpha) / beta;
    float scal = 1.f / (alpha - beta);
    float vreg = 0.f;
    if (lane == i + 1) vreg = 1.f;
    else if (lane >= i + 2 && lane < 16) {
      vreg = acol * scal;
      A[lane][i] = vreg;   // persist householder vector (lane-local write)
    }
    eel[lane][i] = beta;
    ttl[lane][i] = taui;
    // w = taui * A_sub * v
    float wr = 0.f;
    for (int cI = i + 1; cI < 16; ++cI) {
      float vc = __shfl(vreg, cI);
      if (lane >= i + 1 && lane < 16) wr += A[lane][cI] * vc;
    }
    wr *= taui;
    float dot = wsum64((lane >= i + 1 && lane < 16) ? wr * vreg : 0.f);
    float alpha2 = -0.5f * taui * dot;
    wr += alpha2 * vreg;
    // A_sub -= v w^T + w v^T   (symmetric-exact full update, lane-local rows)
    for (int cI = i + 1; cI < 16; ++cI) {
      float wc = __shfl(wr, cI);
      float vc = __shfl(vreg, cI);
      if (lane >= i + 1 && lane < 16) A[lane][cI] -= vreg * wc + wr * vc;
    }
  }

  // gather d into per-lane replicated arrays
  float di = (lane < 16) ? A[lane][lane] : 0.f;
  for (int j = 0; j < 16; ++j) ddl[lane][j] = __shfl(di, j);

  float* dd = ddl[lane];
  float* ee = eel[lane];

  // ---- ssteqr('I') ----
  int m, l, lsv, lend, lendsv;
  int jtot = 0;
  const int nmaxit = 16 * 30;
  int l1 = 0;

outer:
  if (l1 > 15) goto done;
  if (l1 > 0) ee[l1 - 1] = 0.f;
  {
    int mm;
    for (mm = l1; mm < 15; ++mm) {
      float tst = fabsf(ee[mm]);
      if (tst == 0.f) break;
      if (tst <= (sqrtf(fabsf(dd[mm])) * sqrtf(fabsf(dd[mm + 1]))) * EPSF) {
        ee[mm] = 0.f;
        break;
      }
    }
    m = mm;
  }
  l = l1; lsv = l; lend = m; lendsv = lend;
  l1 = m + 1;
  if (lend == l) goto outer;
  {
    float an = 0.f;
    for (int k2 = l; k2 <= lend; ++k2) an = fmaxf(an, fabsf(dd[k2]));
    for (int k2 = l; k2 < lend; ++k2) an = fmaxf(an, fabsf(ee[k2]));
    if (an == 0.f) goto outer;
  }
  if (fabsf(dd[lend]) < fabsf(dd[l])) { lend = lsv; l = lendsv; }

  if (lend > l) {
    // ----- QL -----
ql_top:
    {
      int mm;
      for (mm = l; mm < lend; ++mm) {
        float tst = ee[mm] * ee[mm];
        if (tst <= (EPS2F * fabsf(dd[mm])) * fabsf(dd[mm + 1]) + SAFMINF) break;
      }
      m = mm;
    }
    if (m < lend) ee[m] = 0.f;
    {
      float p = dd[l];
      if (m == l) {
        dd[l] = p;
        l = l + 1;
        if (l <= lend) goto ql_top;
        goto blk_done;
      }
      if (m == l + 1) {
        float rt1, rt2, c2, s2;
        slaev2(dd[l], ee[l], dd[l + 1], &rt1, &rt2, &c2, &s2);
        if (lane < 16) {
          float zj = Zr[lane][l], zj1 = Zr[lane][l + 1];
          Zr[lane][l]     = c2 * zj + s2 * zj1;
          Zr[lane][l + 1] = -s2 * zj + c2 * zj1;
        }
        dd[l] = rt1; dd[l + 1] = rt2; ee[l] = 0.f;
        l += 2;
        if (l <= lend) goto ql_top;
        goto blk_done;
      }
      if (jtot == nmaxit) goto blk_done;
      jtot++;
      float g = (dd[l + 1] - p) / (2.f * ee[l]);
      float r = slapy2(g, 1.f);
      g = dd[m] - p + ee[l] / (g + ssign(r, g));
      float s = 1.f, c = 1.f;
      p = 0.f;
      for (int i = m - 1; i >= l; --i) {
        float f = s * ee[i];
        float bb = c * ee[i];
        slartg(g, f, &c, &s, &r);
        if (i != m - 1) ee[i + 1] = r;
        g = dd[i + 1] - p;
        r = (dd[i] - g) * s + 2.f * c * bb;
        p = s * r;
        dd[i + 1] = g + p;
        g = c * r - bb;
        if (lane < 16) {  // stored rotation (c, -s), slasr 'R','V','B'
          float zj = Zr[lane][i], zj1 = Zr[lane][i + 1];
          Zr[lane][i]     = c * zj - s * zj1;
          Zr[lane][i + 1] = s * zj + c * zj1;
        }
      }
      dd[l] -= p;
      ee[l] = g;
    }
    goto ql_top;
  } else {
    // ----- QR -----
qr_top:
    {
      int mm;
      for (mm = l; mm > lend; --mm) {
        float tst = ee[mm - 1] * ee[mm - 1];
        if (tst <= (EPS2F * fabsf(dd[mm])) * fabsf(dd[mm - 1]) + SAFMINF) break;
      }
      m = mm;
    }
    if (m > lend) ee[m - 1] = 0.f;
    {
      float p = dd[l];
      if (m == l) {
        dd[l] = p;
        l = l - 1;
        if (l >= lend) goto qr_top;
        goto blk_done;
      }
      if (m == l - 1) {
        float rt1, rt2, c2, s2;
        slaev2(dd[l - 1], ee[l - 1], dd[l], &rt1, &rt2, &c2, &s2);
        if (lane < 16) {
          float zj = Zr[lane][l - 1], zj1 = Zr[lane][l];
          Zr[lane][l - 1] = c2 * zj + s2 * zj1;
          Zr[lane][l]     = -s2 * zj + c2 * zj1;
        }
        dd[l - 1] = rt1; dd[l] = rt2; ee[l - 1] = 0.f;
        l -= 2;
        if (l >= lend) goto qr_top;
        goto blk_done;
      }
      if (jtot == nmaxit) goto blk_done;
      jtot++;
      float g = (dd[l - 1] - p) / (2.f * ee[l - 1]);
      float r = slapy2(g, 1.f);
      g = dd[m] - p + ee[l - 1] / (g + ssign(r, g));
      float s = 1.f, c = 1.f;
      p = 0.f;
      for (int i = m; i <= l - 1; ++i) {
        float f = s * ee[i];
        float bb = c * ee[i];
        slartg(g, f, &c, &s, &r);
        if (i != m) ee[i - 1] = r;
        g = dd[i] - p;
        r = (dd[i + 1] - g) * s + 2.f * c * bb;
        p = s * r;
        dd[i] = g + p;
        g = c * r - bb;
        if (lane < 16) {  // stored rotation (c, s), slasr 'R','V','F'
          float zj = Zr[lane][i], zj1 = Zr[lane][i + 1];
          Zr[lane][i]     = c * zj + s * zj1;
          Zr[lane][i + 1] = -s * zj + c * zj1;   // sign fixed: col_{i+1} <- c*col_{i+1} - s*col_i
        }
      }
      dd[l] -= p;
      ee[l - 1] = g;
    }
    goto qr_top;
  }
blk_done:
  goto outer;

done:;
  // top eigenvalue/vector (ascending sort's last column == argmax)
  int kmax = 0;
  float dmax = dd[0];
  for (int j = 1; j < 16; ++j) {
    float dj = dd[j];
    if (dj > dmax) { dmax = dj; kmax = j; }
  }
  float vreg = (lane < 16) ? Zr[lane][kmax] : 0.f;
  // back-transform: v := H(0) H(1) ... H(14) v  (apply H(14) first)
  for (int i = 14; i >= 0; --i) {
    float taui = ttl[lane][i];
    if (taui == 0.f) continue;
    float contrib;
    if (lane == i + 1) contrib = vreg;
    else if (lane >= i + 2 && lane < 16) contrib = A[lane][i] * vreg;
    else contrib = 0.f;
    float dot = wsum64(contrib);
    float td = taui * dot;
    if (lane == i + 1) vreg -= td;
    else if (lane >= i + 2 && lane < 16) vreg -= td * A[lane][i];
  }

  float act = 1.f / (1.f + expf(-(dmax / trace - bias[pid & 31])));
  if (lane == 0) out[pid] = act;
  if (lane < 16) out[512 + pid * 16 + lane] = vreg;
}

extern "C" void kernel_launch(void* const* d_in, const int* in_sizes, int n_in,
                              void* d_out, int out_size, void* d_ws, size_t ws_size,
                              hipStream_t stream) {
  const float* in   = (const float*)d_in[0];   // [16,14,14,544] fp32
  const float* W    = (const float*)d_in[1];   // [1,32,32,4,4] fp32
  const float* bias = (const float*)d_in[2];   // [32] fp32
  float* out = (float*)d_out;

  float* Mbuf = (float*)d_ws;            // 512*256 floats = 512 KB
  float* Gbuf = Mbuf + 512 * 256;        // 512*256 floats = 512 KB

  moments_kernel<<<512, 256, 0, stream>>>(in, Mbuf);
  gram_kernel<<<512, 256, 0, stream>>>(Mbuf, W, Gbuf);
  eig_kernel<<<512, 64, 0, stream>>>(Gbuf, bias, out);
}